// Round 1
// baseline (1060.377 us; speedup 1.0000x reference)
//
#include <hip/hip_runtime.h>
#include <hip/hip_bf16.h>

#define DEVI __device__ __forceinline__

constexpr int B_ = 32, CI = 128, CM = 256, H_ = 32, W_ = 32, HQ = 16, WQ = 16;
constexpr int S_ = 1024, SQ = 256, NB = 100;
constexpr float LAMF = 0.7f, ILAMF = 0.3f, SCALEF = 3.0f;

DEVI float waveSum(float v) {
#pragma unroll
    for (int off = 32; off > 0; off >>= 1) v += __shfl_down(v, off, 64);
    return v;
}

DEVI float blockSum256(float v, float* lds4) {
    v = waveSum(v);
    int wid = threadIdx.x >> 6, lane = threadIdx.x & 63;
    __syncthreads();
    if (lane == 0) lds4[wid] = v;
    __syncthreads();
    return lds4[0] + lds4[1] + lds4[2] + lds4[3];
}

DEVI float blockSum128(float v, float* lds2) {
    v = waveSum(v);
    int wid = threadIdx.x >> 6, lane = threadIdx.x & 63;
    __syncthreads();
    if (lane == 0) lds2[wid] = v;
    __syncthreads();
    return lds2[0] + lds2[1];
}

DEVI float blockMax128(float v, float* lds2) {
#pragma unroll
    for (int off = 32; off > 0; off >>= 1) v = fmaxf(v, __shfl_down(v, off, 64));
    int wid = threadIdx.x >> 6, lane = threadIdx.x & 63;
    __syncthreads();
    if (lane == 0) lds2[wid] = v;
    __syncthreads();
    return fmaxf(lds2[0], lds2[1]);
}

// Transpose weights: W[oc][ic][kh][kw] -> wt[ic][tap][oc] for uniform (scalar) loads.
__global__ __launch_bounds__(256) void k_prep_w(const float* __restrict__ We,
                                                const float* __restrict__ Wf,
                                                const float* __restrict__ Wd,
                                                float* __restrict__ wt1,
                                                float* __restrict__ wt2,
                                                float* __restrict__ wt3) {
    int i = blockIdx.x * 256 + threadIdx.x;  // grid covers 294912 exactly
    {   // wt1: [128][9][256] from W_enc[256][128][3][3]
        int oc = i & 255; int rest = i >> 8; int k = rest % 9; int ic = rest / 9;
        wt1[i] = We[((size_t)oc * CI + ic) * 9 + k];
    }
    {   // wt2/wt3: [256][9][128] from [128][256][3][3]
        int oc = i & 127; int rest = i >> 7; int k = rest % 9; int ic = rest / 9;
        wt2[i] = Wf[((size_t)oc * CM + ic) * 9 + k];
        wt3[i] = Wd[((size_t)oc * CM + ic) * 9 + k];
    }
}

// Proxies: Pn = 3*l2norm(P,axis=-1); store transposed PnT[e][k] + pn2[k]=sum(Pn^2)
__global__ __launch_bounds__(128) void k_prox(const float* __restrict__ P,
                                              float* __restrict__ PnT,
                                              float* __restrict__ pn2) {
    __shared__ float lds2[2];
    int k = blockIdx.x, t = threadIdx.x;
    float v = P[k * CI + t];
    float ss = blockSum128(v * v, lds2);
    float sc = SCALEF / fmaxf(sqrtf(ss), 1e-12f);
    float pv = v * sc;
    PnT[t * NB + k] = pv;
    float s2 = blockSum128(pv * pv, lds2);
    if (t == 0) pn2[k] = s2;
}

// conv1: x(32,128,32,32) * W_enc stride2 SAME(pad lo0 hi1) -> relu -> c(32,256,16,16)
__global__ __launch_bounds__(256) void k_conv1(const float* __restrict__ x,
                                               const float* __restrict__ wt,  // [ic][tap][256]
                                               float* __restrict__ co) {
    int blk = blockIdx.x;           // 32 * 16
    int b = blk >> 4, ocg = blk & 15, oc0 = ocg * 16;
    int t = threadIdx.x;
    int oh = t >> 4, ow = t & 15;
    float acc[16];
#pragma unroll
    for (int i = 0; i < 16; ++i) acc[i] = 0.f;
    const float* xb = x + (size_t)b * CI * H_ * W_;
    for (int ic = 0; ic < CI; ++ic) {
        const float* xp = xb + ic * H_ * W_;
        float xv[9];
#pragma unroll
        for (int kh = 0; kh < 3; ++kh) {
            int ih = 2 * oh + kh;
#pragma unroll
            for (int kw = 0; kw < 3; ++kw) {
                int iw = 2 * ow + kw;
                xv[kh * 3 + kw] = (ih < H_ && iw < W_) ? xp[ih * W_ + iw] : 0.f;
            }
        }
        const float* wp = wt + (size_t)ic * 9 * CM + oc0;
#pragma unroll
        for (int k = 0; k < 9; ++k) {
            float xs = xv[k];
            const float* w16 = wp + k * CM;
#pragma unroll
            for (int o = 0; o < 16; ++o) acc[o] = fmaf(xs, w16[o], acc[o]);
        }
    }
    float* cb = co + (size_t)b * CM * SQ;
#pragma unroll
    for (int o = 0; o < 16; ++o) cb[(oc0 + o) * SQ + t] = fmaxf(acc[o], 0.f);
}

// conv2: c(32,256,16,16) * W_feat stride1 SAME -> relu -> spatial mean -> feat(b,128)
__global__ __launch_bounds__(256) void k_conv2_feat(const float* __restrict__ ci,
                                                    const float* __restrict__ wt,  // [ic][tap][128]
                                                    float* __restrict__ featset) {
    __shared__ float lds4[4];
    int blk = blockIdx.x;           // 32 * 16
    int b = blk >> 4, ocg = blk & 15, oc0 = ocg * 8;
    int t = threadIdx.x;
    int oh = t >> 4, ow = t & 15;
    float acc[8];
#pragma unroll
    for (int i = 0; i < 8; ++i) acc[i] = 0.f;
    const float* cb = ci + (size_t)b * CM * SQ;
    for (int ic = 0; ic < CM; ++ic) {
        const float* cp = cb + ic * SQ;
        float xv[9];
#pragma unroll
        for (int kh = 0; kh < 3; ++kh) {
            int ih = oh + kh - 1;
#pragma unroll
            for (int kw = 0; kw < 3; ++kw) {
                int iw = ow + kw - 1;
                xv[kh * 3 + kw] = (ih >= 0 && ih < HQ && iw >= 0 && iw < WQ) ? cp[ih * WQ + iw] : 0.f;
            }
        }
        const float* wp = wt + (size_t)ic * 9 * CI + oc0;
#pragma unroll
        for (int k = 0; k < 9; ++k) {
            float xs = xv[k];
            const float* w8 = wp + k * CI;
#pragma unroll
            for (int o = 0; o < 8; ++o) acc[o] = fmaf(xs, w8[o], acc[o]);
        }
    }
#pragma unroll
    for (int o = 0; o < 8; ++o) {
        float s = blockSum256(fmaxf(acc[o], 0.f), lds4);
        if (t == 0) featset[b * CI + oc0 + o] = s * (1.f / 256.f);
    }
}

// conv_transpose stride2 SAME (JAX: dilate lhs by 2, pad (2,1)) + fused MSE partials.
__global__ __launch_bounds__(256) void k_deconv_recon(const float* __restrict__ ci,
                                                      const float* __restrict__ wt,  // [ic][tap][128]
                                                      const float* __restrict__ x,
                                                      float* __restrict__ part) {
    __shared__ float lds4[4];
    int blk = blockIdx.x;           // 32 * 16
    int b = blk >> 4, ocg = blk & 15, oc0 = ocg * 8;
    int t = threadIdx.x;
    int r = t >> 4, cc = t & 15;    // this thread owns output 2x2 block at (2r, 2cc)
    float acc[8][4];
#pragma unroll
    for (int o = 0; o < 8; ++o)
#pragma unroll
        for (int p = 0; p < 4; ++p) acc[o][p] = 0.f;
    const float* cb = ci + (size_t)b * CM * SQ;
    // tap = ky*3+kx; which output position (py*2+px) and which c-neighbor it feeds:
    constexpr int POS[9]  = {0, 1, 0, 2, 3, 2, 0, 1, 0};
    constexpr int CSEL[9] = {0, 1, 1, 2, 3, 3, 2, 3, 3};
    for (int ic = 0; ic < CM; ++ic) {
        const float* cp = cb + ic * SQ;
        float cv[4];
        cv[0] = (r > 0 && cc > 0) ? cp[(r - 1) * WQ + cc - 1] : 0.f;
        cv[1] = (r > 0) ? cp[(r - 1) * WQ + cc] : 0.f;
        cv[2] = (cc > 0) ? cp[r * WQ + cc - 1] : 0.f;
        cv[3] = cp[r * WQ + cc];
        const float* wp = wt + (size_t)ic * 9 * CI + oc0;
#pragma unroll
        for (int tap = 0; tap < 9; ++tap) {
            float cvv = cv[CSEL[tap]];
            const float* w8 = wp + tap * CI;
#pragma unroll
            for (int o = 0; o < 8; ++o) acc[o][POS[tap]] = fmaf(cvv, w8[o], acc[o][POS[tap]]);
        }
    }
    float s = 0.f;
#pragma unroll
    for (int o = 0; o < 8; ++o) {
#pragma unroll
        for (int p = 0; p < 4; ++p) {
            int y = 2 * r + (p >> 1), xc = 2 * cc + (p & 1);
            float xv = x[(((size_t)b * CI + oc0 + o) * H_ + y) * W_ + xc];
            float d = acc[o][p] - xv;
            s += d * d;
        }
    }
    s = blockSum256(s, lds4);
    if (t == 0) part[blk] = s;
}

// 1 / max(||x[b,:,s]||, 1e-12) per spatial position
__global__ __launch_bounds__(256) void k_invd(const float* __restrict__ x, float* __restrict__ invd) {
    int idx = blockIdx.x * 256 + threadIdx.x;  // 32768
    int b = idx >> 10, s = idx & 1023;
    const float* xb = x + (size_t)b * CI * S_ + s;
    float ss = 0.f;
    for (int c = 0; c < CI; ++c) { float v = xb[c * S_]; ss = fmaf(v, v, ss); }
    invd[idx] = 1.f / fmaxf(sqrtf(ss), 1e-12f);
}

// meanx[b,c] = mean_s x ; meanfl[b,c] = mean_s x*invd
__global__ __launch_bounds__(256) void k_meanred(const float* __restrict__ x,
                                                 const float* __restrict__ invd,
                                                 float* __restrict__ meanx,
                                                 float* __restrict__ meanfl) {
    __shared__ float lds4[4];
    int blk = blockIdx.x;          // 32 * 16
    int b = blk >> 4, cg = blk & 15, c0 = cg * 8;
    int t = threadIdx.x;
    float sx[8], sf[8];
#pragma unroll
    for (int c = 0; c < 8; ++c) { sx[c] = 0.f; sf[c] = 0.f; }
    const float* xb = x + (size_t)b * CI * S_;
    const float* ivb = invd + b * S_;
#pragma unroll
    for (int j = 0; j < 4; ++j) {
        int s = t + j * 256;
        float iv = ivb[s];
#pragma unroll
        for (int c = 0; c < 8; ++c) {
            float v = xb[(c0 + c) * S_ + s];
            sx[c] += v; sf[c] = fmaf(v, iv, sf[c]);
        }
    }
#pragma unroll
    for (int c = 0; c < 8; ++c) {
        float a1 = blockSum256(sx[c], lds4);
        float a2 = blockSum256(sf[c], lds4);
        if (t == 0) {
            meanx[b * CI + c0 + c] = a1 * (1.f / 1024.f);
            meanfl[b * CI + c0 + c] = a2 * (1.f / 1024.f);
        }
    }
}

// feat_ma = lam*mean(xa) + (1-lam)*mean(l2norm_ch(xb)); feat_mb symmetric.
// (T's column sums == v exactly; mean of row sums == 1/S exactly -> Sinkhorn is dead code.)
__global__ void k_mix(const float* __restrict__ mxa, const float* __restrict__ mxb,
                      const float* __restrict__ mfa, const float* __restrict__ mfb,
                      float* __restrict__ feats) {
    int i = blockIdx.x * 256 + threadIdx.x;  // 4096
    feats[2 * B_ * CI + i] = LAMF * mxa[i] + ILAMF * mfb[i];
    feats[3 * B_ * CI + i] = LAMF * mxb[i] + ILAMF * mfa[i];
}

// metric loss pieces per (set, b): lse of -D row, D at la[b], D at lb[b]
__global__ __launch_bounds__(128) void k_metric(const float* __restrict__ feats,
                                                const float* __restrict__ PnT,
                                                const float* __restrict__ pn2,
                                                const int* __restrict__ la,
                                                const int* __restrict__ lb,
                                                float* __restrict__ mo) {
    __shared__ float lds2[2];
    __shared__ float xs[128];
    int blk = blockIdx.x;          // 4 sets * 32 b
    int set = blk >> 5, b = blk & 31;
    int t = threadIdx.x;
    float xv = feats[((size_t)set * B_ + b) * CI + t];
    float ss = blockSum128(xv * xv, lds2);
    float sc = SCALEF / fmaxf(sqrtf(ss), 1e-12f);
    float xn = xv * sc;
    xs[t] = xn;
    float xn2 = blockSum128(xn * xn, lds2);  // has syncthreads -> xs visible
    bool active = (t < NB);
    float Dk = 1e30f;
    if (active) {
        float dot = 0.f;
#pragma unroll 8
        for (int e = 0; e < CI; ++e) dot = fmaf(xs[e], PnT[e * NB + t], dot);
        Dk = xn2 + pn2[t] - 2.f * dot;
    }
    float z = active ? -Dk : -1e30f;
    float m = blockMax128(z, lds2);
    float e = active ? expf(z - m) : 0.f;
    float se = blockSum128(e, lds2);
    float lse = m + logf(se);
    if (t == 0) mo[blk * 3 + 0] = lse;
    int A = la[b], Bb = lb[b];
    if (t == A) mo[blk * 3 + 1] = Dk;
    if (t == Bb) mo[blk * 3 + 2] = Dk;
}

__global__ __launch_bounds__(256) void k_final(const float* __restrict__ pa,
                                               const float* __restrict__ pb,
                                               const float* __restrict__ mo,
                                               float* __restrict__ out) {
    __shared__ float lds4[4];
    __shared__ float mla[4], mlb[4];
    int t = threadIdx.x;
    float sa = blockSum256(pa[t] + pa[t + 256], lds4);
    float sb = blockSum256(pb[t] + pb[t + 256], lds4);
    float lxa = sa * (1.f / 4194304.f), lxb = sb * (1.f / 4194304.f);
    float ula = 0.f, ulb = 0.f;
    if (t < 128) {
        const float* m = mo + t * 3;   // t = set*32 + b
        ula = m[0] + m[1];             // lse + D[la]  (loss term)
        ulb = m[0] + m[2];             // lse + D[lb]
    }
#pragma unroll
    for (int off = 16; off > 0; off >>= 1) {
        ula += __shfl_down(ula, off, 32);
        ulb += __shfl_down(ulb, off, 32);
    }
    if (t < 128 && (t & 31) == 0) { mla[t >> 5] = ula * (1.f / 32.f); mlb[t >> 5] = ulb * (1.f / 32.f); }
    __syncthreads();
    if (t == 0) {
        float lca = mla[0];                           // metric(feat_xa, la)
        float lcb = mlb[1];                           // metric(feat_xb, lb)
        float lcma = LAMF * mla[2] + ILAMF * mlb[2];  // feat_ma: lam*la + (1-lam)*lb
        float lcmb = LAMF * mlb[3] + ILAMF * mla[3];  // feat_mb: lam*lb + (1-lam)*la
        out[0] = lxa + lxb + lca + lcb + lcma + lcmb;
        out[1] = lxa; out[2] = lxb; out[3] = lca; out[4] = lcb; out[5] = lcma; out[6] = lcmb;
    }
}

extern "C" void kernel_launch(void* const* d_in, const int* in_sizes, int n_in,
                              void* d_out, int out_size, void* d_ws, size_t ws_size,
                              hipStream_t stream) {
    const float* xa = (const float*)d_in[0];
    const float* xb = (const float*)d_in[1];
    const int* la = (const int*)d_in[2];
    const int* lb = (const int*)d_in[3];
    const float* P = (const float*)d_in[4];
    const float* We = (const float*)d_in[5];
    const float* Wf = (const float*)d_in[6];
    const float* Wd = (const float*)d_in[7];
    float* ws = (float*)d_ws;

    float* c_a = ws;                    // 2,097,152
    float* c_b = c_a + 2097152;         // 2,097,152
    float* wt1 = c_b + 2097152;         // 294,912
    float* wt2 = wt1 + 294912;          // 294,912
    float* wt3 = wt2 + 294912;          // 294,912
    float* PnT = wt3 + 294912;          // 12,800
    float* pn2 = PnT + 12800;           // 100
    float* feats = pn2 + 100;           // 16,384 ([4][32][128])
    float* mxa = feats + 16384;         // 4,096
    float* mxb = mxa + 4096;
    float* mfa = mxb + 4096;
    float* mfb = mfa + 4096;
    float* iva = mfb + 4096;            // 32,768
    float* ivb = iva + 32768;           // 32,768
    float* pra = ivb + 32768;           // 512
    float* prb = pra + 512;             // 512
    float* mo = prb + 512;              // 384
    float* out = (float*)d_out;

    k_prep_w<<<1152, 256, 0, stream>>>(We, Wf, Wd, wt1, wt2, wt3);
    k_prox<<<NB, 128, 0, stream>>>(P, PnT, pn2);
    k_conv1<<<512, 256, 0, stream>>>(xa, wt1, c_a);
    k_conv1<<<512, 256, 0, stream>>>(xb, wt1, c_b);
    k_conv2_feat<<<512, 256, 0, stream>>>(c_a, wt2, feats);
    k_conv2_feat<<<512, 256, 0, stream>>>(c_b, wt2, feats + 4096);
    k_deconv_recon<<<512, 256, 0, stream>>>(c_a, wt3, xa, pra);
    k_deconv_recon<<<512, 256, 0, stream>>>(c_b, wt3, xb, prb);
    k_invd<<<128, 256, 0, stream>>>(xa, iva);
    k_invd<<<128, 256, 0, stream>>>(xb, ivb);
    k_meanred<<<512, 256, 0, stream>>>(xa, iva, mxa, mfa);
    k_meanred<<<512, 256, 0, stream>>>(xb, ivb, mxb, mfb);
    k_mix<<<16, 256, 0, stream>>>(mxa, mxb, mfa, mfb, feats);
    k_metric<<<128, 128, 0, stream>>>(feats, PnT, pn2, la, lb, mo);
    k_final<<<1, 256, 0, stream>>>(pra, prb, mo, out);
}

// Round 2
// 246.543 us; speedup vs baseline: 4.3010x; 4.3010x over previous
//
#include <hip/hip_runtime.h>
#include <hip/hip_bf16.h>

#define DEVI __device__ __forceinline__

constexpr int B_ = 32, CI = 128, CM = 256, H_ = 32, W_ = 32;
constexpr int S_ = 1024, NB = 100;
constexpr float LAMF = 0.7f, ILAMF = 0.3f, SCALEF = 3.0f;

typedef short bf8 __attribute__((ext_vector_type(8)));
typedef float f4 __attribute__((ext_vector_type(4)));
typedef unsigned short u16;

struct alignas(8) us4 { u16 v[4]; };

DEVI u16 f2bf(float f) {
    unsigned u = __builtin_bit_cast(unsigned, f);
    u += 0x7FFFu + ((u >> 16) & 1u);
    return (u16)(u >> 16);
}

DEVI float waveSum(float v) {
#pragma unroll
    for (int off = 32; off > 0; off >>= 1) v += __shfl_down(v, off, 64);
    return v;
}

DEVI float blockSum256(float v, float* lds4) {
    v = waveSum(v);
    int wid = threadIdx.x >> 6, lane = threadIdx.x & 63;
    __syncthreads();
    if (lane == 0) lds4[wid] = v;
    __syncthreads();
    return lds4[0] + lds4[1] + lds4[2] + lds4[3];
}

DEVI float blockSum128(float v, float* lds2) {
    v = waveSum(v);
    int wid = threadIdx.x >> 6, lane = threadIdx.x & 63;
    __syncthreads();
    if (lane == 0) lds2[wid] = v;
    __syncthreads();
    return lds2[0] + lds2[1];
}

DEVI float blockMax128(float v, float* lds2) {
#pragma unroll
    for (int off = 32; off > 0; off >>= 1) v = fmaxf(v, __shfl_down(v, off, 64));
    int wid = threadIdx.x >> 6, lane = threadIdx.x & 63;
    __syncthreads();
    if (lane == 0) lds2[wid] = v;
    __syncthreads();
    return fmaxf(lds2[0], lds2[1]);
}

// ---- weight prep: bf16 [oc][tap][ic] ----
__global__ __launch_bounds__(256) void k_prep_w(const float* __restrict__ We,
                                                const float* __restrict__ Wf,
                                                const float* __restrict__ Wd,
                                                u16* __restrict__ A1,
                                                u16* __restrict__ A2,
                                                u16* __restrict__ A3) {
    int i = blockIdx.x * 256 + threadIdx.x;  // 294912
    {   // A1: [256][9][128] from We[256][128][9]
        int ic = i & 127, tap = (i >> 7) % 9, oc = i / 1152;
        A1[i] = f2bf(We[((size_t)oc * CI + ic) * 9 + tap]);
    }
    {   // A2/A3: [128][9][256] from [128][256][9]
        int ic = i & 255, tap = (i >> 8) % 9, oc = i / 2304;
        A2[i] = f2bf(Wf[((size_t)oc * CM + ic) * 9 + tap]);
        A3[i] = f2bf(Wd[((size_t)oc * CM + ic) * 9 + tap]);
    }
}

// ---- proxies ----
__global__ __launch_bounds__(128) void k_prox(const float* __restrict__ P,
                                              float* __restrict__ PnT,
                                              float* __restrict__ pn2) {
    __shared__ float lds2[2];
    int k = blockIdx.x, t = threadIdx.x;
    float v = P[k * CI + t];
    float ss = blockSum128(v * v, lds2);
    float sc = SCALEF / fmaxf(sqrtf(ss), 1e-12f);
    float pv = v * sc;
    PnT[t * NB + k] = pv;
    float s2 = blockSum128(pv * pv, lds2);
    if (t == 0) pn2[k] = s2;
}

// ---- x -> bf16 channel-last padded [ab][32][34][34][128] ----
__global__ __launch_bounds__(256) void k_xpose(const float* __restrict__ xa,
                                               const float* __restrict__ xb,
                                               u16* __restrict__ xpad) {
    __shared__ float tile[8][33];
    int b = blockIdx.x, y = blockIdx.y, ab = blockIdx.z;
    const float* x = (ab ? xb : xa) + (size_t)b * CI * S_ + y * W_;
    u16* o = xpad + (size_t)ab * (32 * 34 * 34 * 128) + ((size_t)b * 34 + y) * 34 * 128;
    int t = threadIdx.x;
    int ics = t >> 5, xx = t & 31;
    int xw = t >> 3, icw = t & 7;
    for (int ic0 = 0; ic0 < CI; ic0 += 8) {
        __syncthreads();
        tile[ics][xx] = x[(size_t)(ic0 + ics) * S_ + xx];
        __syncthreads();
        o[xw * 128 + ic0 + icw] = f2bf(tile[icw][xw]);
    }
}

// ---- conv1 MFMA: xpad * A1 -> relu -> cpad [ab][32][18][18][256] ----
__global__ __launch_bounds__(256) void k_conv1(const u16* __restrict__ xpad,
                                               const u16* __restrict__ A1,
                                               u16* __restrict__ cpad) {
    int t = threadIdx.x, lane = t & 63;
    int wid = t >> 6, wm = wid & 1, wn = wid >> 1;
    int l16 = lane & 15, lq = lane >> 4;
    int mt = blockIdx.x, nb = blockIdx.y, ab = blockIdx.z;
    int b = nb >> 1;
    int m0w = mt * 64 + wm * 32;
    int ohb = (nb & 1) * 8 + wn * 4;
    const u16* xp = xpad + (size_t)ab * (32 * 34 * 34 * 128);
    u16* cp = cpad + (size_t)ab * (32 * 18 * 18 * 256);
    const u16* a0 = A1 + (size_t)(m0w + l16) * 1152 + lq * 8;
    const u16* bl = xp + ((size_t)b * 34 * 34 + 2 * l16) * 128 + lq * 8;
    f4 acc[2][4] = {};
    for (int tap = 0; tap < 9; ++tap) {
        int ky = tap / 3, kx = tap % 3;
        const u16* at0 = a0 + tap * 128;
        const u16* at1 = at0 + 16 * 1152;
        const u16* bt0 = bl + ((2 * (ohb + 0) + ky) * 34 + kx) * 128;
        const u16* bt1 = bl + ((2 * (ohb + 1) + ky) * 34 + kx) * 128;
        const u16* bt2 = bl + ((2 * (ohb + 2) + ky) * 34 + kx) * 128;
        const u16* bt3 = bl + ((2 * (ohb + 3) + ky) * 34 + kx) * 128;
#pragma unroll
        for (int cc = 0; cc < 4; ++cc) {
            bf8 av0 = *(const bf8*)(at0 + cc * 32);
            bf8 av1 = *(const bf8*)(at1 + cc * 32);
            bf8 bv0 = *(const bf8*)(bt0 + cc * 32);
            bf8 bv1 = *(const bf8*)(bt1 + cc * 32);
            bf8 bv2 = *(const bf8*)(bt2 + cc * 32);
            bf8 bv3 = *(const bf8*)(bt3 + cc * 32);
            acc[0][0] = __builtin_amdgcn_mfma_f32_16x16x32_bf16(av0, bv0, acc[0][0], 0, 0, 0);
            acc[0][1] = __builtin_amdgcn_mfma_f32_16x16x32_bf16(av0, bv1, acc[0][1], 0, 0, 0);
            acc[0][2] = __builtin_amdgcn_mfma_f32_16x16x32_bf16(av0, bv2, acc[0][2], 0, 0, 0);
            acc[0][3] = __builtin_amdgcn_mfma_f32_16x16x32_bf16(av0, bv3, acc[0][3], 0, 0, 0);
            acc[1][0] = __builtin_amdgcn_mfma_f32_16x16x32_bf16(av1, bv0, acc[1][0], 0, 0, 0);
            acc[1][1] = __builtin_amdgcn_mfma_f32_16x16x32_bf16(av1, bv1, acc[1][1], 0, 0, 0);
            acc[1][2] = __builtin_amdgcn_mfma_f32_16x16x32_bf16(av1, bv2, acc[1][2], 0, 0, 0);
            acc[1][3] = __builtin_amdgcn_mfma_f32_16x16x32_bf16(av1, bv3, acc[1][3], 0, 0, 0);
        }
    }
#pragma unroll
    for (int f = 0; f < 4; ++f) {
        int oh = ohb + f;
        u16* co = cp + (((size_t)b * 18 + 1 + oh) * 18 + 1 + l16) * 256 + m0w + lq * 4;
#pragma unroll
        for (int mf = 0; mf < 2; ++mf) {
            us4 pk;
#pragma unroll
            for (int r = 0; r < 4; ++r) pk.v[r] = f2bf(fmaxf(acc[mf][f][r], 0.f));
            *(us4*)(co + mf * 16) = pk;
        }
    }
}

// ---- conv2 MFMA: cpad * A2 -> relu -> spatial-mean feats (atomic) ----
__global__ __launch_bounds__(256) void k_conv2(const u16* __restrict__ cpad,
                                               const u16* __restrict__ A2,
                                               float* __restrict__ feats) {
    int t = threadIdx.x, lane = t & 63;
    int wid = t >> 6, wm = wid & 1, wn = wid >> 1;
    int l16 = lane & 15, lq = lane >> 4;
    int mt = blockIdx.x, nb = blockIdx.y, ab = blockIdx.z;
    int b = nb >> 1;
    int m0w = mt * 64 + wm * 32;
    int ohb = (nb & 1) * 8 + wn * 4;
    const u16* cp = cpad + (size_t)ab * (32 * 18 * 18 * 256);
    const u16* a0 = A2 + (size_t)(m0w + l16) * 2304 + lq * 8;
    const u16* bl = cp + ((size_t)b * 18 * 18 + l16) * 256 + lq * 8;
    f4 acc[2][4] = {};
    for (int tap = 0; tap < 9; ++tap) {
        int ky = tap / 3, kx = tap % 3;
        const u16* at0 = a0 + tap * 256;
        const u16* at1 = at0 + 16 * 2304;
        const u16* bt0 = bl + (((ohb + 0) + ky) * 18 + kx) * 256;
        const u16* bt1 = bl + (((ohb + 1) + ky) * 18 + kx) * 256;
        const u16* bt2 = bl + (((ohb + 2) + ky) * 18 + kx) * 256;
        const u16* bt3 = bl + (((ohb + 3) + ky) * 18 + kx) * 256;
#pragma unroll
        for (int cc = 0; cc < 8; ++cc) {
            bf8 av0 = *(const bf8*)(at0 + cc * 32);
            bf8 av1 = *(const bf8*)(at1 + cc * 32);
            bf8 bv0 = *(const bf8*)(bt0 + cc * 32);
            bf8 bv1 = *(const bf8*)(bt1 + cc * 32);
            bf8 bv2 = *(const bf8*)(bt2 + cc * 32);
            bf8 bv3 = *(const bf8*)(bt3 + cc * 32);
            acc[0][0] = __builtin_amdgcn_mfma_f32_16x16x32_bf16(av0, bv0, acc[0][0], 0, 0, 0);
            acc[0][1] = __builtin_amdgcn_mfma_f32_16x16x32_bf16(av0, bv1, acc[0][1], 0, 0, 0);
            acc[0][2] = __builtin_amdgcn_mfma_f32_16x16x32_bf16(av0, bv2, acc[0][2], 0, 0, 0);
            acc[0][3] = __builtin_amdgcn_mfma_f32_16x16x32_bf16(av0, bv3, acc[0][3], 0, 0, 0);
            acc[1][0] = __builtin_amdgcn_mfma_f32_16x16x32_bf16(av1, bv0, acc[1][0], 0, 0, 0);
            acc[1][1] = __builtin_amdgcn_mfma_f32_16x16x32_bf16(av1, bv1, acc[1][1], 0, 0, 0);
            acc[1][2] = __builtin_amdgcn_mfma_f32_16x16x32_bf16(av1, bv2, acc[1][2], 0, 0, 0);
            acc[1][3] = __builtin_amdgcn_mfma_f32_16x16x32_bf16(av1, bv3, acc[1][3], 0, 0, 0);
        }
    }
    float* fo = feats + (size_t)ab * (B_ * CI) + b * CI;
#pragma unroll
    for (int mf = 0; mf < 2; ++mf)
#pragma unroll
        for (int r = 0; r < 4; ++r) {
            float v = 0.f;
#pragma unroll
            for (int f = 0; f < 4; ++f) v += fmaxf(acc[mf][f][r], 0.f);
            v += __shfl_xor(v, 1, 64);
            v += __shfl_xor(v, 2, 64);
            v += __shfl_xor(v, 4, 64);
            v += __shfl_xor(v, 8, 64);
            if (l16 == 0) atomicAdd(fo + m0w + mf * 16 + lq * 4 + r, v * (1.f / 256.f));
        }
}

// ---- deconv MFMA (4 parity GEMMs) + fused MSE ----
__global__ __launch_bounds__(256) void k_deconv(const u16* __restrict__ cpad,
                                                const u16* __restrict__ A3,
                                                const float* __restrict__ xa,
                                                const float* __restrict__ xb,
                                                float* __restrict__ pr) {
    __shared__ float lds4[4];
    int t = threadIdx.x, lane = t & 63;
    int wid = t >> 6, wm = wid & 1, wn = wid >> 1;
    int l16 = lane & 15, lq = lane >> 4;
    int mt = blockIdx.x, nb = blockIdx.y;
    int par = blockIdx.z >> 1, ab = blockIdx.z & 1;
    int py = par >> 1, px = par & 1;
    int b = nb >> 1;
    int m0w = mt * 64 + wm * 32;
    int ohb = (nb & 1) * 8 + wn * 4;
    const u16* cp = cpad + (size_t)ab * (32 * 18 * 18 * 256);
    const u16* a0 = A3 + (size_t)(m0w + l16) * 2304 + lq * 8;
    const u16* bl = cp + ((size_t)b * 18 * 18 + l16) * 256 + lq * 8;
    f4 acc[2][4] = {};
    int nky = py ? 1 : 2, nkx = px ? 1 : 2;
    for (int i = 0; i < nky; ++i) {
        int ky = py ? 1 : i * 2;
        int dy = ky ? 1 : 0;
        for (int j = 0; j < nkx; ++j) {
            int kx = px ? 1 : j * 2;
            int dx = kx ? 1 : 0;
            int tap = ky * 3 + kx;
            const u16* at0 = a0 + tap * 256;
            const u16* at1 = at0 + 16 * 2304;
            const u16* bt0 = bl + (((ohb + 0) + dy) * 18 + dx) * 256;
            const u16* bt1 = bl + (((ohb + 1) + dy) * 18 + dx) * 256;
            const u16* bt2 = bl + (((ohb + 2) + dy) * 18 + dx) * 256;
            const u16* bt3 = bl + (((ohb + 3) + dy) * 18 + dx) * 256;
#pragma unroll
            for (int cc = 0; cc < 8; ++cc) {
                bf8 av0 = *(const bf8*)(at0 + cc * 32);
                bf8 av1 = *(const bf8*)(at1 + cc * 32);
                bf8 bv0 = *(const bf8*)(bt0 + cc * 32);
                bf8 bv1 = *(const bf8*)(bt1 + cc * 32);
                bf8 bv2 = *(const bf8*)(bt2 + cc * 32);
                bf8 bv3 = *(const bf8*)(bt3 + cc * 32);
                acc[0][0] = __builtin_amdgcn_mfma_f32_16x16x32_bf16(av0, bv0, acc[0][0], 0, 0, 0);
                acc[0][1] = __builtin_amdgcn_mfma_f32_16x16x32_bf16(av0, bv1, acc[0][1], 0, 0, 0);
                acc[0][2] = __builtin_amdgcn_mfma_f32_16x16x32_bf16(av0, bv2, acc[0][2], 0, 0, 0);
                acc[0][3] = __builtin_amdgcn_mfma_f32_16x16x32_bf16(av0, bv3, acc[0][3], 0, 0, 0);
                acc[1][0] = __builtin_amdgcn_mfma_f32_16x16x32_bf16(av1, bv0, acc[1][0], 0, 0, 0);
                acc[1][1] = __builtin_amdgcn_mfma_f32_16x16x32_bf16(av1, bv1, acc[1][1], 0, 0, 0);
                acc[1][2] = __builtin_amdgcn_mfma_f32_16x16x32_bf16(av1, bv2, acc[1][2], 0, 0, 0);
                acc[1][3] = __builtin_amdgcn_mfma_f32_16x16x32_bf16(av1, bv3, acc[1][3], 0, 0, 0);
            }
        }
    }
    const float* x = ab ? xb : xa;
    float ss = 0.f;
#pragma unroll
    for (int f = 0; f < 4; ++f) {
        int Y = 2 * (ohb + f) + py;
        int X = 2 * l16 + px;
#pragma unroll
        for (int mf = 0; mf < 2; ++mf)
#pragma unroll
            for (int r = 0; r < 4; ++r) {
                int m = m0w + mf * 16 + lq * 4 + r;
                float xv = x[(((size_t)b * CI + m) * H_ + Y) * W_ + X];
                float d = acc[mf][f][r] - xv;
                ss = fmaf(d, d, ss);
            }
    }
    ss = blockSum256(ss, lds4);
    if (t == 0) atomicAdd(pr + ab, ss);
}

// ---- channel-norm + means (unchanged from R0) ----
__global__ __launch_bounds__(256) void k_invd(const float* __restrict__ x, float* __restrict__ invd) {
    int idx = blockIdx.x * 256 + threadIdx.x;
    int b = idx >> 10, s = idx & 1023;
    const float* xb = x + (size_t)b * CI * S_ + s;
    float ss = 0.f;
    for (int c = 0; c < CI; ++c) { float v = xb[c * S_]; ss = fmaf(v, v, ss); }
    invd[idx] = 1.f / fmaxf(sqrtf(ss), 1e-12f);
}

__global__ __launch_bounds__(256) void k_meanred(const float* __restrict__ x,
                                                 const float* __restrict__ invd,
                                                 float* __restrict__ meanx,
                                                 float* __restrict__ meanfl) {
    __shared__ float lds4[4];
    int blk = blockIdx.x;
    int b = blk >> 4, cg = blk & 15, c0 = cg * 8;
    int t = threadIdx.x;
    float sx[8], sf[8];
#pragma unroll
    for (int c = 0; c < 8; ++c) { sx[c] = 0.f; sf[c] = 0.f; }
    const float* xb = x + (size_t)b * CI * S_;
    const float* ivb = invd + b * S_;
#pragma unroll
    for (int j = 0; j < 4; ++j) {
        int s = t + j * 256;
        float iv = ivb[s];
#pragma unroll
        for (int c = 0; c < 8; ++c) {
            float v = xb[(c0 + c) * S_ + s];
            sx[c] += v; sf[c] = fmaf(v, iv, sf[c]);
        }
    }
#pragma unroll
    for (int c = 0; c < 8; ++c) {
        float a1 = blockSum256(sx[c], lds4);
        float a2 = blockSum256(sf[c], lds4);
        if (t == 0) {
            meanx[b * CI + c0 + c] = a1 * (1.f / 1024.f);
            meanfl[b * CI + c0 + c] = a2 * (1.f / 1024.f);
        }
    }
}

__global__ void k_mix(const float* __restrict__ mxa, const float* __restrict__ mxb,
                      const float* __restrict__ mfa, const float* __restrict__ mfb,
                      float* __restrict__ feats) {
    int i = blockIdx.x * 256 + threadIdx.x;
    feats[2 * B_ * CI + i] = LAMF * mxa[i] + ILAMF * mfb[i];
    feats[3 * B_ * CI + i] = LAMF * mxb[i] + ILAMF * mfa[i];
}

__global__ __launch_bounds__(128) void k_metric(const float* __restrict__ feats,
                                                const float* __restrict__ PnT,
                                                const float* __restrict__ pn2,
                                                const int* __restrict__ la,
                                                const int* __restrict__ lb,
                                                float* __restrict__ mo) {
    __shared__ float lds2[2];
    __shared__ float xs[128];
    int blk = blockIdx.x;
    int t = threadIdx.x;
    float xv = feats[(size_t)blk * CI + t];
    float ss = blockSum128(xv * xv, lds2);
    float sc = SCALEF / fmaxf(sqrtf(ss), 1e-12f);
    float xn = xv * sc;
    xs[t] = xn;
    float xn2 = blockSum128(xn * xn, lds2);
    bool active = (t < NB);
    float Dk = 1e30f;
    if (active) {
        float dot = 0.f;
#pragma unroll 8
        for (int e = 0; e < CI; ++e) dot = fmaf(xs[e], PnT[e * NB + t], dot);
        Dk = xn2 + pn2[t] - 2.f * dot;
    }
    float z = active ? -Dk : -1e30f;
    float m = blockMax128(z, lds2);
    float e = active ? expf(z - m) : 0.f;
    float se = blockSum128(e, lds2);
    float lse = m + logf(se);
    int b = blk & 31;
    if (t == 0) mo[blk * 3 + 0] = lse;
    int A = la[b], Bb = lb[b];
    if (t == A) mo[blk * 3 + 1] = Dk;
    if (t == Bb) mo[blk * 3 + 2] = Dk;
}

__global__ __launch_bounds__(128) void k_final(const float* __restrict__ pr,
                                               const float* __restrict__ mo,
                                               float* __restrict__ out) {
    __shared__ float mla[4], mlb[4];
    int t = threadIdx.x;
    const float* m = mo + t * 3;
    float ula = m[0] + m[1];
    float ulb = m[0] + m[2];
#pragma unroll
    for (int off = 16; off > 0; off >>= 1) {
        ula += __shfl_down(ula, off, 32);
        ulb += __shfl_down(ulb, off, 32);
    }
    if ((t & 31) == 0) { mla[t >> 5] = ula * (1.f / 32.f); mlb[t >> 5] = ulb * (1.f / 32.f); }
    __syncthreads();
    if (t == 0) {
        float lxa = pr[0] * (1.f / 4194304.f);
        float lxb = pr[1] * (1.f / 4194304.f);
        float lca = mla[0];
        float lcb = mlb[1];
        float lcma = LAMF * mla[2] + ILAMF * mlb[2];
        float lcmb = LAMF * mlb[3] + ILAMF * mla[3];
        out[0] = lxa + lxb + lca + lcb + lcma + lcmb;
        out[1] = lxa; out[2] = lxb; out[3] = lca; out[4] = lcb; out[5] = lcma; out[6] = lcmb;
    }
}

extern "C" void kernel_launch(void* const* d_in, const int* in_sizes, int n_in,
                              void* d_out, int out_size, void* d_ws, size_t ws_size,
                              hipStream_t stream) {
    const float* xa = (const float*)d_in[0];
    const float* xb = (const float*)d_in[1];
    const int* la = (const int*)d_in[2];
    const int* lb = (const int*)d_in[3];
    const float* P = (const float*)d_in[4];
    const float* We = (const float*)d_in[5];
    const float* Wf = (const float*)d_in[6];
    const float* Wd = (const float*)d_in[7];

    char* w = (char*)d_ws;
    const size_t XPAD_B = (size_t)2 * 32 * 34 * 34 * 128 * 2;   // 18,939,904
    const size_t CPAD_B = (size_t)2 * 32 * 18 * 18 * 256 * 2;   // 10,616,832
    const size_t AW_B = (size_t)294912 * 2;                     // 589,824
    u16* xpad = (u16*)w;                 w += XPAD_B;
    u16* cpad = (u16*)w;                 w += CPAD_B;
    u16* A1 = (u16*)w;                   w += AW_B;
    u16* A2 = (u16*)w;                   w += AW_B;
    u16* A3 = (u16*)w;                   w += AW_B;
    float* PnT = (float*)w;              w += 12800 * 4;
    float* pn2 = (float*)w;              w += 128 * 4;
    float* feats = (float*)w;            w += 16384 * 4;        // [4][32][128]
    float* mxa = (float*)w;              w += 4096 * 4;
    float* mxb = (float*)w;              w += 4096 * 4;
    float* mfa = (float*)w;              w += 4096 * 4;
    float* mfb = (float*)w;              w += 4096 * 4;
    float* iva = (float*)w;              w += 32768 * 4;
    float* ivb = (float*)w;              w += 32768 * 4;
    float* pr = (float*)w;               w += 16 * 4;
    float* mo = (float*)w;               w += 384 * 4;
    float* out = (float*)d_out;

    hipMemsetAsync(xpad, 0, XPAD_B, stream);
    hipMemsetAsync(cpad, 0, CPAD_B, stream);
    hipMemsetAsync(feats, 0, 2 * B_ * CI * sizeof(float), stream);
    hipMemsetAsync(pr, 0, 2 * sizeof(float), stream);

    k_prep_w<<<1152, 256, 0, stream>>>(We, Wf, Wd, A1, A2, A3);
    k_prox<<<NB, 128, 0, stream>>>(P, PnT, pn2);
    k_xpose<<<dim3(32, 32, 2), 256, 0, stream>>>(xa, xb, xpad);
    k_conv1<<<dim3(4, 64, 2), 256, 0, stream>>>(xpad, A1, cpad);
    k_conv2<<<dim3(2, 64, 2), 256, 0, stream>>>(cpad, A2, feats);
    k_deconv<<<dim3(2, 64, 8), 256, 0, stream>>>(cpad, A3, xa, xb, pr);
    k_invd<<<128, 256, 0, stream>>>(xa, iva);
    k_invd<<<128, 256, 0, stream>>>(xb, ivb);
    k_meanred<<<512, 256, 0, stream>>>(xa, iva, mxa, mfa);
    k_meanred<<<512, 256, 0, stream>>>(xb, ivb, mxb, mfb);
    k_mix<<<16, 256, 0, stream>>>(mxa, mxb, mfa, mfb, feats);
    k_metric<<<128, 128, 0, stream>>>(feats, PnT, pn2, la, lb, mo);
    k_final<<<1, 128, 0, stream>>>(pr, mo, out);
}

// Round 3
// 202.734 us; speedup vs baseline: 5.2304x; 1.2161x over previous
//
#include <hip/hip_runtime.h>
#include <hip/hip_bf16.h>

#define DEVI __device__ __forceinline__

constexpr int B_ = 32, CI = 128, CM = 256, H_ = 32, W_ = 32;
constexpr int S_ = 1024, NB = 100;
constexpr float LAMF = 0.7f, ILAMF = 0.3f, SCALEF = 3.0f;
constexpr size_t XSZ = (size_t)32 * 34 * 34 * 128;   // per-ab xpad elements
constexpr size_t CSZ = (size_t)32 * 18 * 18 * 256;   // per-ab cpad elements

typedef short bf8 __attribute__((ext_vector_type(8)));
typedef float f16v __attribute__((ext_vector_type(16)));
typedef unsigned short u16;

struct alignas(8) us4 { u16 v[4]; };
struct alignas(16) us8 { u16 v[8]; };

DEVI u16 f2bf(float f) {
    unsigned u = __builtin_bit_cast(unsigned, f);
    u += 0x7FFFu + ((u >> 16) & 1u);
    return (u16)(u >> 16);
}
DEVI float bf2f(u16 h) {
    unsigned u = ((unsigned)h) << 16;
    return __builtin_bit_cast(float, u);
}

DEVI float waveSum(float v) {
#pragma unroll
    for (int off = 32; off > 0; off >>= 1) v += __shfl_down(v, off, 64);
    return v;
}
DEVI float blockSum256(float v, float* lds4) {
    v = waveSum(v);
    int wid = threadIdx.x >> 6, lane = threadIdx.x & 63;
    __syncthreads();
    if (lane == 0) lds4[wid] = v;
    __syncthreads();
    return lds4[0] + lds4[1] + lds4[2] + lds4[3];
}
DEVI float blockSum128(float v, float* lds2) {
    v = waveSum(v);
    int wid = threadIdx.x >> 6, lane = threadIdx.x & 63;
    __syncthreads();
    if (lane == 0) lds2[wid] = v;
    __syncthreads();
    return lds2[0] + lds2[1];
}
DEVI float blockMax128(float v, float* lds2) {
#pragma unroll
    for (int off = 32; off > 0; off >>= 1) v = fmaxf(v, __shfl_down(v, off, 64));
    int wid = threadIdx.x >> 6, lane = threadIdx.x & 63;
    __syncthreads();
    if (lane == 0) lds2[wid] = v;
    __syncthreads();
    return fmaxf(lds2[0], lds2[1]);
}

// ---- weight prep via LDS transpose: coalesced read AND write ----
// A1: [256 oc][9 tap][128 ic]  from We[oc][ic][tap]
// A2/A3: [128 oc][9 tap][256 ic] from Wf/Wd[oc][ic][tap]
__global__ __launch_bounds__(256) void k_prep_w(const float* __restrict__ We,
                                                const float* __restrict__ Wf,
                                                const float* __restrict__ Wd,
                                                u16* __restrict__ A1,
                                                u16* __restrict__ A2,
                                                u16* __restrict__ A3) {
    __shared__ float w1[2][2304];
    int blk = blockIdx.x, t = threadIdx.x;
    if (blk < 256) {
        const float* src = We + (size_t)blk * 1152;
#pragma unroll
        for (int i = 0; i < 5; ++i) { int j = i * 256 + t; if (j < 1152) w1[0][j] = src[j]; }
        __syncthreads();
        u16* dst = A1 + (size_t)blk * 1152;
#pragma unroll
        for (int i = 0; i < 5; ++i) {
            int j = i * 256 + t;
            if (j < 1152) { int ic = j & 127, tap = j >> 7; dst[j] = f2bf(w1[0][ic * 9 + tap]); }
        }
    } else {
        int oc = blk - 256;
        const float* s2 = Wf + (size_t)oc * 2304;
        const float* s3 = Wd + (size_t)oc * 2304;
#pragma unroll
        for (int i = 0; i < 9; ++i) { int j = i * 256 + t; w1[0][j] = s2[j]; w1[1][j] = s3[j]; }
        __syncthreads();
#pragma unroll
        for (int i = 0; i < 9; ++i) {
            int j = i * 256 + t;
            int ic = j & 255, tap = j >> 8;
            A2[(size_t)oc * 2304 + j] = f2bf(w1[0][ic * 9 + tap]);
            A3[(size_t)oc * 2304 + j] = f2bf(w1[1][ic * 9 + tap]);
        }
    }
}

// ---- proxies ----
__global__ __launch_bounds__(128) void k_prox(const float* __restrict__ P,
                                              float* __restrict__ PnT,
                                              float* __restrict__ pn2) {
    __shared__ float lds2[2];
    int k = blockIdx.x, t = threadIdx.x;
    float v = P[k * CI + t];
    float ss = blockSum128(v * v, lds2);
    float sc = SCALEF / fmaxf(sqrtf(ss), 1e-12f);
    float pv = v * sc;
    PnT[t * NB + k] = pv;
    float s2 = blockSum128(pv * pv, lds2);
    if (t == 0) pn2[k] = s2;
}

// ---- fused: x -> bf16 channel-last xpad  +  invd (LDS-only)  +  meanx/meanfl ----
// grid (32 b, 16 yg, 2 ab); block covers 64 spatial positions (2 rows), all 128 ch.
__global__ __launch_bounds__(256) void k_xpose(const float* __restrict__ xa,
                                               const float* __restrict__ xb,
                                               u16* __restrict__ xpad,
                                               float* __restrict__ meanbuf) {
    __shared__ float ldsx[128][64];   // 32KB
    __shared__ float sred[256];
    __shared__ float sinv[64];
    int b = blockIdx.x, yg = blockIdx.y, ab = blockIdx.z;
    int t = threadIdx.x;
    const float* x = (ab ? xb : xa) + (size_t)b * CI * S_ + yg * 64;
    int c4 = t >> 6, p = t & 63;
    // coalesced load: wave = one channel's 64 positions
    for (int c0 = 0; c0 < 32; ++c0) {
        int c = c0 * 4 + c4;
        ldsx[c][p] = x[(size_t)c * S_ + p];
    }
    __syncthreads();
    // pack bf16 (channel-last) + partial sum-of-squares (this thread: 32 channels of position p)
    int qc = t >> 6;                      // channel quarter
    int y = yg * 2 + (p >> 5), xcol = p & 31;
    u16* ox = xpad + (size_t)ab * XSZ + ((size_t)(b * 34 + y) * 34 + xcol) * 128;
    float ss = 0.f;
#pragma unroll
    for (int c8 = 0; c8 < 4; ++c8) {
        int cb = qc * 32 + c8 * 8;
        us8 pk;
#pragma unroll
        for (int j = 0; j < 8; ++j) {
            float v = ldsx[cb + j][p];
            ss = fmaf(v, v, ss);
            pk.v[j] = f2bf(v);
        }
        *(us8*)(ox + cb) = pk;
    }
    sred[t] = ss;
    __syncthreads();
    if (t < 64) {
        float s = sred[t] + sred[t + 64] + sred[t + 128] + sred[t + 192];
        sinv[t] = 1.f / fmaxf(sqrtf(s), 1e-12f);
    }
    __syncthreads();
    // means: thread handles channel c = t>>1, half h = t&1 (32 positions each)
    int c = t >> 1, h = t & 1;
    float sx = 0.f, sf = 0.f;
    for (int i = 0; i < 32; ++i) {
        int p2 = h * 32 + ((i + c) & 31);   // stagger to avoid bank conflicts
        float v = ldsx[c][p2];
        sx += v;
        sf = fmaf(v, sinv[p2], sf);
    }
    sx += __shfl_xor(sx, 1, 64);
    sf += __shfl_xor(sf, 1, 64);
    if (!(t & 1)) {
        atomicAdd(&meanbuf[(size_t)ab * 4096 + b * 128 + c], sx * (1.f / 1024.f));
        atomicAdd(&meanbuf[8192 + (size_t)ab * 4096 + b * 128 + c], sf * (1.f / 1024.f));
    }
}

// ---- conv1 (32x32x16 MFMA): xpad * A1 -> relu -> cpad ----
// grid (4 mt, 32 b, 2 ab); wave: m 64 (mf2) x n 64 (nf2); block n-span 256 (all positions)
__global__ __launch_bounds__(256) void k_conv1(const u16* __restrict__ xpad,
                                               const u16* __restrict__ A1,
                                               u16* __restrict__ cpad) {
    int t = threadIdx.x, l = t & 63, l31 = l & 31, lq = l >> 5;
    int wid = t >> 6;
    int mt = blockIdx.x, b = blockIdx.y, ab = blockIdx.z;
    int m0 = mt * 64;
    const u16* xp = xpad + (size_t)ab * XSZ;
    const u16* aB = A1 + (size_t)(m0 + l31) * 1152 + lq * 8;
    int n0 = wid * 64 + l31, n1 = n0 + 32;
    int oh0 = n0 >> 4, ow0 = n0 & 15;
    int oh1 = n1 >> 4, ow1 = n1 & 15;
    const u16* bB0 = xp + ((size_t)(b * 34 + 2 * oh0) * 34 + 2 * ow0) * 128 + lq * 8;
    const u16* bB1 = xp + ((size_t)(b * 34 + 2 * oh1) * 34 + 2 * ow1) * 128 + lq * 8;
    f16v acc[2][2] = {};
#pragma unroll
    for (int tap = 0; tap < 9; ++tap) {
        const int ky = tap / 3, kx = tap % 3;
        const int aoff = tap * 128, boff = (ky * 34 + kx) * 128;
#pragma unroll
        for (int cc = 0; cc < 8; ++cc) {
            bf8 a0 = *(const bf8*)(aB + aoff + cc * 16);
            bf8 a1 = *(const bf8*)(aB + 36864 + aoff + cc * 16);
            bf8 b0 = *(const bf8*)(bB0 + boff + cc * 16);
            bf8 b1 = *(const bf8*)(bB1 + boff + cc * 16);
            acc[0][0] = __builtin_amdgcn_mfma_f32_32x32x16_bf16(a0, b0, acc[0][0], 0, 0, 0);
            acc[0][1] = __builtin_amdgcn_mfma_f32_32x32x16_bf16(a0, b1, acc[0][1], 0, 0, 0);
            acc[1][0] = __builtin_amdgcn_mfma_f32_32x32x16_bf16(a1, b0, acc[1][0], 0, 0, 0);
            acc[1][1] = __builtin_amdgcn_mfma_f32_32x32x16_bf16(a1, b1, acc[1][1], 0, 0, 0);
        }
    }
    u16* cp = cpad + (size_t)ab * CSZ;
#pragma unroll
    for (int nf = 0; nf < 2; ++nf) {
        int oh = nf ? oh1 : oh0, ow = nf ? ow1 : ow0;
        u16* o = cp + ((size_t)(b * 18 + 1 + oh) * 18 + 1 + ow) * 256 + m0 + 4 * lq;
#pragma unroll
        for (int mf = 0; mf < 2; ++mf)
#pragma unroll
            for (int rg = 0; rg < 4; ++rg) {
                us4 pk;
#pragma unroll
                for (int j = 0; j < 4; ++j) pk.v[j] = f2bf(fmaxf(acc[mf][nf][rg * 4 + j], 0.f));
                *(us4*)(o + mf * 32 + rg * 8) = pk;
            }
    }
}

// ---- conv2 (32x32x16): cpad * A2 -> relu -> spatial-mean feats (atomic) ----
// grid (4: mt|ng, 32 b, 2 ab); wave: m 64 (mf2) x n 32
__global__ __launch_bounds__(256) void k_conv2(const u16* __restrict__ cpad,
                                               const u16* __restrict__ A2,
                                               float* __restrict__ feats) {
    int t = threadIdx.x, l = t & 63, l31 = l & 31, lq = l >> 5;
    int wid = t >> 6;
    int mt = blockIdx.x & 1, ng = blockIdx.x >> 1;
    int b = blockIdx.y, ab = blockIdx.z;
    int m0 = mt * 64;
    int n = ng * 128 + wid * 32 + l31;
    int oh = n >> 4, ow = n & 15;
    const u16* aB = A2 + (size_t)(m0 + l31) * 2304 + lq * 8;
    const u16* bB = cpad + (size_t)ab * CSZ + ((size_t)(b * 18 + oh) * 18 + ow) * 256 + lq * 8;
    f16v acc[2] = {};
#pragma unroll
    for (int tap = 0; tap < 9; ++tap) {
        const int ky = tap / 3, kx = tap % 3;
        const int aoff = tap * 256, boff = (ky * 18 + kx) * 256;
#pragma unroll
        for (int cc = 0; cc < 16; ++cc) {
            bf8 a0 = *(const bf8*)(aB + aoff + cc * 16);
            bf8 a1 = *(const bf8*)(aB + 73728 + aoff + cc * 16);
            bf8 bv = *(const bf8*)(bB + boff + cc * 16);
            acc[0] = __builtin_amdgcn_mfma_f32_32x32x16_bf16(a0, bv, acc[0], 0, 0, 0);
            acc[1] = __builtin_amdgcn_mfma_f32_32x32x16_bf16(a1, bv, acc[1], 0, 0, 0);
        }
    }
    float* fo = feats + (size_t)ab * 4096 + b * 128;
#pragma unroll
    for (int mf = 0; mf < 2; ++mf)
#pragma unroll
        for (int r = 0; r < 16; ++r) {
            float v = fmaxf(acc[mf][r], 0.f);
            v += __shfl_xor(v, 1, 64);
            v += __shfl_xor(v, 2, 64);
            v += __shfl_xor(v, 4, 64);
            v += __shfl_xor(v, 8, 64);
            v += __shfl_xor(v, 16, 64);
            if (l31 == 0)
                atomicAdd(fo + m0 + mf * 32 + (r & 3) + 8 * (r >> 2) + 4 * lq, v * (1.f / 256.f));
        }
}

// ---- deconv (32x32x16, all 4 parities merged) + fused MSE vs bf16 xpad ----
// grid (4 ng, 32 b, 2 ab); waves (wm2 x wn2): m 64 (mf2) x n 32 (2 oh rows)
__global__ __launch_bounds__(256) void k_deconv(const u16* __restrict__ cpad,
                                                const u16* __restrict__ A3,
                                                const u16* __restrict__ xpad,
                                                float* __restrict__ pr) {
    __shared__ float lds4[4];
    int t = threadIdx.x, l = t & 63, l31 = l & 31, lq = l >> 5;
    int wid = t >> 6, wm = wid & 1, wn = wid >> 1;
    int ng = blockIdx.x, b = blockIdx.y, ab = blockIdx.z;
    int m0w = wm * 64;
    int oh = ng * 4 + wn * 2 + (l31 >> 4), ow = l31 & 15;
    const u16* aB = A3 + (size_t)(m0w + l31) * 2304 + lq * 8;
    const u16* bB = cpad + (size_t)ab * CSZ + ((size_t)(b * 18 + oh) * 18 + ow) * 256 + lq * 8;
    f16v acc[2][4] = {};
#pragma unroll
    for (int tap = 0; tap < 9; ++tap) {
        const int ky = tap / 3, kx = tap % 3;
        const int dy = (ky + 1) >> 1, dx = (kx + 1) >> 1;
        const int par = (ky & 1) * 2 + (kx & 1);
        const int aoff = tap * 256, boff = (dy * 18 + dx) * 256;
#pragma unroll
        for (int cc = 0; cc < 16; ++cc) {
            bf8 a0 = *(const bf8*)(aB + aoff + cc * 16);
            bf8 a1 = *(const bf8*)(aB + 73728 + aoff + cc * 16);
            bf8 bv = *(const bf8*)(bB + boff + cc * 16);
            acc[0][par] = __builtin_amdgcn_mfma_f32_32x32x16_bf16(a0, bv, acc[0][par], 0, 0, 0);
            acc[1][par] = __builtin_amdgcn_mfma_f32_32x32x16_bf16(a1, bv, acc[1][par], 0, 0, 0);
        }
    }
    const u16* xq = xpad + (size_t)ab * XSZ;
    float ss = 0.f;
#pragma unroll
    for (int par = 0; par < 4; ++par) {
        int py = par >> 1, px = par & 1;
        int Y = 2 * oh + py, X = 2 * ow + px;
        const u16* xb = xq + ((size_t)(b * 34 + Y) * 34 + X) * 128 + m0w + 4 * lq;
#pragma unroll
        for (int mf = 0; mf < 2; ++mf)
#pragma unroll
            for (int rg = 0; rg < 4; ++rg) {
                us4 x4 = *(const us4*)(xb + mf * 32 + rg * 8);
#pragma unroll
                for (int j = 0; j < 4; ++j) {
                    float d = acc[mf][par][rg * 4 + j] - bf2f(x4.v[j]);
                    ss = fmaf(d, d, ss);
                }
            }
    }
    ss = blockSum256(ss, lds4);
    if (t == 0) atomicAdd(pr + ab, ss);
}

// ---- mix (Sinkhorn is provably dead code: colsums==v, mean rowsums==1/S) ----
__global__ void k_mix(const float* __restrict__ mxa, const float* __restrict__ mxb,
                      const float* __restrict__ mfa, const float* __restrict__ mfb,
                      float* __restrict__ feats) {
    int i = blockIdx.x * 256 + threadIdx.x;
    feats[2 * B_ * CI + i] = LAMF * mxa[i] + ILAMF * mfb[i];
    feats[3 * B_ * CI + i] = LAMF * mxb[i] + ILAMF * mfa[i];
}

__global__ __launch_bounds__(128) void k_metric(const float* __restrict__ feats,
                                                const float* __restrict__ PnT,
                                                const float* __restrict__ pn2,
                                                const int* __restrict__ la,
                                                const int* __restrict__ lb,
                                                float* __restrict__ mo) {
    __shared__ float lds2[2];
    __shared__ float xs[128];
    int blk = blockIdx.x;
    int t = threadIdx.x;
    float xv = feats[(size_t)blk * CI + t];
    float ss = blockSum128(xv * xv, lds2);
    float sc = SCALEF / fmaxf(sqrtf(ss), 1e-12f);
    float xn = xv * sc;
    xs[t] = xn;
    float xn2 = blockSum128(xn * xn, lds2);
    bool active = (t < NB);
    float Dk = 1e30f;
    if (active) {
        float dot = 0.f;
#pragma unroll 8
        for (int e = 0; e < CI; ++e) dot = fmaf(xs[e], PnT[e * NB + t], dot);
        Dk = xn2 + pn2[t] - 2.f * dot;
    }
    float z = active ? -Dk : -1e30f;
    float m = blockMax128(z, lds2);
    float e = active ? expf(z - m) : 0.f;
    float se = blockSum128(e, lds2);
    float lse = m + logf(se);
    int b = blk & 31;
    if (t == 0) mo[blk * 3 + 0] = lse;
    int A = la[b], Bb = lb[b];
    if (t == A) mo[blk * 3 + 1] = Dk;
    if (t == Bb) mo[blk * 3 + 2] = Dk;
}

__global__ __launch_bounds__(128) void k_final(const float* __restrict__ pr,
                                               const float* __restrict__ mo,
                                               float* __restrict__ out) {
    __shared__ float mla[4], mlb[4];
    int t = threadIdx.x;
    const float* m = mo + t * 3;
    float ula = m[0] + m[1];
    float ulb = m[0] + m[2];
#pragma unroll
    for (int off = 16; off > 0; off >>= 1) {
        ula += __shfl_down(ula, off, 32);
        ulb += __shfl_down(ulb, off, 32);
    }
    if ((t & 31) == 0) { mla[t >> 5] = ula * (1.f / 32.f); mlb[t >> 5] = ulb * (1.f / 32.f); }
    __syncthreads();
    if (t == 0) {
        float lxa = pr[0] * (1.f / 4194304.f);
        float lxb = pr[1] * (1.f / 4194304.f);
        float lca = mla[0];
        float lcb = mlb[1];
        float lcma = LAMF * mla[2] + ILAMF * mlb[2];
        float lcmb = LAMF * mlb[3] + ILAMF * mla[3];
        out[0] = lxa + lxb + lca + lcb + lcma + lcmb;
        out[1] = lxa; out[2] = lxb; out[3] = lca; out[4] = lcb; out[5] = lcma; out[6] = lcmb;
    }
}

extern "C" void kernel_launch(void* const* d_in, const int* in_sizes, int n_in,
                              void* d_out, int out_size, void* d_ws, size_t ws_size,
                              hipStream_t stream) {
    const float* xa = (const float*)d_in[0];
    const float* xb = (const float*)d_in[1];
    const int* la = (const int*)d_in[2];
    const int* lb = (const int*)d_in[3];
    const float* P = (const float*)d_in[4];
    const float* We = (const float*)d_in[5];
    const float* Wf = (const float*)d_in[6];
    const float* Wd = (const float*)d_in[7];

    char* w = (char*)d_ws;
    const size_t XPAD_B = XSZ * 2 * sizeof(u16);     // 18,939,904
    const size_t CPAD_B = CSZ * 2 * sizeof(u16);     // 10,616,832
    const size_t AW_B = (size_t)294912 * 2;          // 589,824 each
    u16* xpad = (u16*)w;                 w += XPAD_B;
    u16* cpad = (u16*)w;                 w += CPAD_B;
    u16* A1 = (u16*)w;                   w += AW_B;
    u16* A2 = (u16*)w;                   w += AW_B;
    u16* A3 = (u16*)w;                   w += AW_B;
    float* PnT = (float*)w;              w += 12800 * 4;
    float* pn2 = (float*)w;              w += 128 * 4;
    float* feats = (float*)w;            w += 16384 * 4;   // [4][32][128]
    float* meanbuf = (float*)w;          w += 16384 * 4;   // [2 kind][2 ab][32][128]
    float* pr = (float*)w;               w += 16 * 4;
    float* mo = (float*)w;               w += 384 * 4;
    float* out = (float*)d_out;

    hipMemsetAsync(xpad, 0, XPAD_B, stream);
    hipMemsetAsync(cpad, 0, CPAD_B, stream);
    hipMemsetAsync(feats, 0, 2 * B_ * CI * sizeof(float), stream);
    hipMemsetAsync(meanbuf, 0, 16384 * sizeof(float), stream);
    hipMemsetAsync(pr, 0, 2 * sizeof(float), stream);

    k_prep_w<<<384, 256, 0, stream>>>(We, Wf, Wd, A1, A2, A3);
    k_prox<<<NB, 128, 0, stream>>>(P, PnT, pn2);
    k_xpose<<<dim3(32, 16, 2), 256, 0, stream>>>(xa, xb, xpad, meanbuf);
    k_conv1<<<dim3(4, 32, 2), 256, 0, stream>>>(xpad, A1, cpad);
    k_conv2<<<dim3(4, 32, 2), 256, 0, stream>>>(cpad, A2, feats);
    k_deconv<<<dim3(4, 32, 2), 256, 0, stream>>>(cpad, A3, xpad, pr);
    k_mix<<<16, 256, 0, stream>>>(meanbuf, meanbuf + 4096, meanbuf + 8192, meanbuf + 12288, feats);
    k_metric<<<128, 128, 0, stream>>>(feats, PnT, pn2, la, lb, mo);
    k_final<<<1, 128, 0, stream>>>(pr, mo, out);
}

// Round 4
// 131.141 us; speedup vs baseline: 8.0858x; 1.5459x over previous
//
#include <hip/hip_runtime.h>
#include <hip/hip_bf16.h>

#define DEVI __device__ __forceinline__

constexpr int B_ = 32, CI = 128, CM = 256, H_ = 32, W_ = 32;
constexpr int S_ = 1024, NB = 100;
constexpr float LAMF = 0.7f, ILAMF = 0.3f, SCALEF = 3.0f;
// chunked channel-last layouts: [b][ch/8][pos][8ch]
constexpr size_t XSZ = (size_t)32 * 16 * 1156 * 8;   // per-ab xpad elems (34x34 pos)
constexpr size_t XBS = (size_t)16 * 1156 * 8;        // per-b stride
constexpr size_t CSZ = (size_t)32 * 32 * 324 * 8;    // per-ab cpad elems (18x18 pos)
constexpr size_t CBS = (size_t)32 * 324 * 8;

typedef short bf8 __attribute__((ext_vector_type(8)));
typedef float f16v __attribute__((ext_vector_type(16)));
typedef unsigned short u16;

struct alignas(8) us4 { u16 v[4]; };
struct alignas(16) us8 { u16 v[8]; };

DEVI u16 f2bf(float f) {
    unsigned u = __builtin_bit_cast(unsigned, f);
    u += 0x7FFFu + ((u >> 16) & 1u);
    return (u16)(u >> 16);
}
DEVI float bf2f(u16 h) {
    unsigned u = ((unsigned)h) << 16;
    return __builtin_bit_cast(float, u);
}

DEVI float waveSum(float v) {
#pragma unroll
    for (int off = 32; off > 0; off >>= 1) v += __shfl_down(v, off, 64);
    return v;
}
DEVI float blockSum256(float v, float* lds4) {
    v = waveSum(v);
    int wid = threadIdx.x >> 6, lane = threadIdx.x & 63;
    __syncthreads();
    if (lane == 0) lds4[wid] = v;
    __syncthreads();
    return lds4[0] + lds4[1] + lds4[2] + lds4[3];
}
DEVI float blockSum128(float v, float* lds2) {
    v = waveSum(v);
    int wid = threadIdx.x >> 6, lane = threadIdx.x & 63;
    __syncthreads();
    if (lane == 0) lds2[wid] = v;
    __syncthreads();
    return lds2[0] + lds2[1];
}
DEVI float blockMax128(float v, float* lds2) {
#pragma unroll
    for (int off = 32; off > 0; off >>= 1) v = fmaxf(v, __shfl_down(v, off, 64));
    int wid = threadIdx.x >> 6, lane = threadIdx.x & 63;
    __syncthreads();
    if (lane == 0) lds2[wid] = v;
    __syncthreads();
    return fmaxf(lds2[0], lds2[1]);
}

// ---- weight prep: fragment-native layouts ----
// A1': [tap9][ks8][oc256][lq2][8ic]  (ic = ks*16+lq*8+e, K/tap=128)
// A2'/A3': [tap9][ks16][oc128][lq2][8ic] (ic = ks*16+lq*8+e, K/tap=256)
__global__ __launch_bounds__(256) void k_prep_w(const float* __restrict__ We,
                                                const float* __restrict__ Wf,
                                                const float* __restrict__ Wd,
                                                u16* __restrict__ A1,
                                                u16* __restrict__ A2,
                                                u16* __restrict__ A3) {
    int i = blockIdx.x * 256 + threadIdx.x;  // 294912
    {
        int e = i & 7, lq = (i >> 3) & 1, oc = (i >> 4) & 255, ks = (i >> 12) & 7, tap = i >> 15;
        int ic = ks * 16 + lq * 8 + e;
        A1[i] = f2bf(We[((size_t)oc * CI + ic) * 9 + tap]);
    }
    {
        int e = i & 7, lq = (i >> 3) & 1, oc = (i >> 4) & 127, ks = (i >> 11) & 15, tap = i >> 15;
        int ic = ks * 16 + lq * 8 + e;
        A2[i] = f2bf(Wf[((size_t)oc * CM + ic) * 9 + tap]);
        A3[i] = f2bf(Wd[((size_t)oc * CM + ic) * 9 + tap]);
    }
}

// ---- proxies ----
__global__ __launch_bounds__(128) void k_prox(const float* __restrict__ P,
                                              float* __restrict__ PnT,
                                              float* __restrict__ pn2) {
    __shared__ float lds2[2];
    int k = blockIdx.x, t = threadIdx.x;
    float v = P[k * CI + t];
    float ss = blockSum128(v * v, lds2);
    float sc = SCALEF / fmaxf(sqrtf(ss), 1e-12f);
    float pv = v * sc;
    PnT[t * NB + k] = pv;
    float s2 = blockSum128(pv * pv, lds2);
    if (t == 0) pn2[k] = s2;
}

// ---- fused: x -> bf16 chunked xpad + invd (LDS-only) + meanx/meanfl ----
__global__ __launch_bounds__(256) void k_xpose(const float* __restrict__ xa,
                                               const float* __restrict__ xb,
                                               u16* __restrict__ xpad,
                                               float* __restrict__ meanbuf) {
    __shared__ float ldsx[128][64];   // 32KB
    __shared__ float sred[256];
    __shared__ float sinv[64];
    int b = blockIdx.x, yg = blockIdx.y, ab = blockIdx.z;
    int t = threadIdx.x;
    const float* x = (ab ? xb : xa) + (size_t)b * CI * S_ + yg * 64;
    int c4 = t >> 6, p = t & 63;
    for (int c0 = 0; c0 < 32; ++c0) {
        int c = c0 * 4 + c4;
        ldsx[c][p] = x[(size_t)c * S_ + p];
    }
    __syncthreads();
    int qc = t >> 6;
    int y = yg * 2 + (p >> 5), xcol = p & 31;
    u16* ox = xpad + (size_t)ab * XSZ + (size_t)b * XBS;
    float ss = 0.f;
#pragma unroll
    for (int c8 = 0; c8 < 4; ++c8) {
        int cb = qc * 32 + c8 * 8;
        int cc = cb >> 3;
        us8 pk;
#pragma unroll
        for (int j = 0; j < 8; ++j) {
            float v = ldsx[cb + j][p];
            ss = fmaf(v, v, ss);
            pk.v[j] = f2bf(v);
        }
        *(us8*)(ox + ((size_t)cc * 1156 + y * 34 + xcol) * 8) = pk;
    }
    sred[t] = ss;
    __syncthreads();
    if (t < 64) {
        float s = sred[t] + sred[t + 64] + sred[t + 128] + sred[t + 192];
        sinv[t] = 1.f / fmaxf(sqrtf(s), 1e-12f);
    }
    __syncthreads();
    int c = t >> 1, h = t & 1;
    float sx = 0.f, sf = 0.f;
    for (int i = 0; i < 32; ++i) {
        int p2 = h * 32 + ((i + c) & 31);
        float v = ldsx[c][p2];
        sx += v;
        sf = fmaf(v, sinv[p2], sf);
    }
    sx += __shfl_xor(sx, 1, 64);
    sf += __shfl_xor(sf, 1, 64);
    if (!(t & 1)) {
        atomicAdd(&meanbuf[(size_t)ab * 4096 + b * 128 + c], sx * (1.f / 1024.f));
        atomicAdd(&meanbuf[8192 + (size_t)ab * 4096 + b * 128 + c], sf * (1.f / 1024.f));
    }
}

// ---- conv1: xpad * A1' -> relu -> cpad. grid (8: mt|nb, 32 b, 2 ab) ----
__global__ __launch_bounds__(256, 2) void k_conv1(const u16* __restrict__ XC,
                                                  const u16* __restrict__ A1,
                                                  u16* __restrict__ CC) {
    int t = threadIdx.x, l = t & 63, l31 = l & 31, lq = l >> 5;
    int wid = t >> 6, wm = wid & 1, wn = wid >> 1;
    int mt = blockIdx.x & 1, nb = blockIdx.x >> 1;
    int b = blockIdx.y, ab = blockIdx.z;
    int oh0 = nb * 4;
    int oc0 = mt * 128 + wm * 64;
    int n = wn * 32 + l31;
    int oh = oh0 + (n >> 4), ow = n & 15;
    const u16* xc = XC + (size_t)ab * XSZ + (size_t)b * XBS;
    const u16* aB = A1 + ((size_t)(oc0 + l31) * 2 + lq) * 8;
    f16v acc[2] = {};
#pragma unroll
    for (int tap = 0; tap < 9; ++tap) {
        const int ky = tap / 3, kx = tap % 3;
        const int pos = (2 * oh + ky) * 34 + 2 * ow + kx;
#pragma unroll
        for (int ks = 0; ks < 8; ++ks) {
            const u16* ap = aB + (size_t)(tap * 8 + ks) * 4096;
            bf8 a0 = *(const bf8*)(ap);
            bf8 a1 = *(const bf8*)(ap + 512);
            bf8 bv = *(const bf8*)(xc + ((size_t)(ks * 2 + lq) * 1156 + pos) * 8);
            acc[0] = __builtin_amdgcn_mfma_f32_32x32x16_bf16(a0, bv, acc[0], 0, 0, 0);
            acc[1] = __builtin_amdgcn_mfma_f32_32x32x16_bf16(a1, bv, acc[1], 0, 0, 0);
        }
    }
    u16* cb = CC + (size_t)ab * CSZ + (size_t)b * CBS;
    int posO = (1 + oh) * 18 + 1 + ow;
#pragma unroll
    for (int mf = 0; mf < 2; ++mf)
#pragma unroll
        for (int rg = 0; rg < 4; ++rg) {
            us4 pk;
#pragma unroll
            for (int j = 0; j < 4; ++j) pk.v[j] = f2bf(fmaxf(acc[mf][rg * 4 + j], 0.f));
            int cc = (oc0 + mf * 32 + 8 * rg) >> 3;
            *(us4*)(cb + ((size_t)cc * 324 + posO) * 8 + 4 * lq) = pk;
        }
}

// ---- merged conv2 (type0: relu+mean->feats) and deconv (type1: MSE->pr) ----
// grid (4 nb, 32 b, 4 z: type=z>>1, ab=z&1)
__global__ __launch_bounds__(256, 2) void k_cde(const u16* __restrict__ CC,
                                                const u16* __restrict__ A2,
                                                const u16* __restrict__ A3,
                                                const u16* __restrict__ XC,
                                                float* __restrict__ feats,
                                                float* __restrict__ pr) {
    __shared__ float lds4[4];
    int t = threadIdx.x, l = t & 63, l31 = l & 31, lq = l >> 5;
    int wid = t >> 6, wm = wid & 1, wn = wid >> 1;
    int nb = blockIdx.x, b = blockIdx.y;
    int type = blockIdx.z >> 1, ab = blockIdx.z & 1;
    int oh0 = nb * 4;
    int m0w = wm * 64;
    int n = wn * 32 + l31;
    int oh = oh0 + (n >> 4), ow = n & 15;
    const u16* cbb = CC + (size_t)ab * CSZ + (size_t)b * CBS;
    if (type == 0) {
        const u16* aB = A2 + ((size_t)(m0w + l31) * 2 + lq) * 8;
        f16v acc[2] = {};
#pragma unroll
        for (int tap = 0; tap < 9; ++tap) {
            const int ky = tap / 3, kx = tap % 3;
            const int pos = (oh + ky) * 18 + ow + kx;
#pragma unroll
            for (int ks = 0; ks < 16; ++ks) {
                const u16* ap = aB + (size_t)(tap * 16 + ks) * 2048;
                bf8 a0 = *(const bf8*)(ap);
                bf8 a1 = *(const bf8*)(ap + 512);
                bf8 bv = *(const bf8*)(cbb + ((size_t)(ks * 2 + lq) * 324 + pos) * 8);
                acc[0] = __builtin_amdgcn_mfma_f32_32x32x16_bf16(a0, bv, acc[0], 0, 0, 0);
                acc[1] = __builtin_amdgcn_mfma_f32_32x32x16_bf16(a1, bv, acc[1], 0, 0, 0);
            }
        }
        float* fo = feats + (size_t)ab * 4096 + b * 128;
#pragma unroll
        for (int mf = 0; mf < 2; ++mf)
#pragma unroll
            for (int r = 0; r < 16; ++r) {
                float v = fmaxf(acc[mf][r], 0.f);
                v += __shfl_xor(v, 1, 64);
                v += __shfl_xor(v, 2, 64);
                v += __shfl_xor(v, 4, 64);
                v += __shfl_xor(v, 8, 64);
                v += __shfl_xor(v, 16, 64);
                if (l31 == 0)
                    atomicAdd(fo + m0w + mf * 32 + (r & 3) + 8 * (r >> 2) + 4 * lq, v * (1.f / 256.f));
            }
    } else {
        const u16* aB = A3 + ((size_t)(m0w + l31) * 2 + lq) * 8;
        f16v acc[2][4] = {};
#pragma unroll
        for (int tap = 0; tap < 9; ++tap) {
            const int ky = tap / 3, kx = tap % 3;
            const int dy = (ky + 1) >> 1, dx = (kx + 1) >> 1;
            const int par = (ky & 1) * 2 + (kx & 1);
            const int pos = (oh + dy) * 18 + ow + dx;
#pragma unroll
            for (int ks = 0; ks < 16; ++ks) {
                const u16* ap = aB + (size_t)(tap * 16 + ks) * 2048;
                bf8 a0 = *(const bf8*)(ap);
                bf8 a1 = *(const bf8*)(ap + 512);
                bf8 bv = *(const bf8*)(cbb + ((size_t)(ks * 2 + lq) * 324 + pos) * 8);
                acc[0][par] = __builtin_amdgcn_mfma_f32_32x32x16_bf16(a0, bv, acc[0][par], 0, 0, 0);
                acc[1][par] = __builtin_amdgcn_mfma_f32_32x32x16_bf16(a1, bv, acc[1][par], 0, 0, 0);
            }
        }
        const u16* xq = XC + (size_t)ab * XSZ + (size_t)b * XBS;
        float ss = 0.f;
#pragma unroll
        for (int par = 0; par < 4; ++par) {
            int py = par >> 1, px = par & 1;
            int Y = 2 * oh + py, X = 2 * ow + px;
#pragma unroll
            for (int mf = 0; mf < 2; ++mf)
#pragma unroll
                for (int rg = 0; rg < 4; ++rg) {
                    int cc = (m0w + mf * 32 + 8 * rg) >> 3;
                    us4 x4 = *(const us4*)(xq + ((size_t)cc * 1156 + Y * 34 + X) * 8 + 4 * lq);
#pragma unroll
                    for (int j = 0; j < 4; ++j) {
                        float d = acc[mf][par][rg * 4 + j] - bf2f(x4.v[j]);
                        ss = fmaf(d, d, ss);
                    }
                }
        }
        ss = blockSum256(ss, lds4);
        if (t == 0) atomicAdd(pr + ab, ss);
    }
}

// ---- mix (Sinkhorn is dead code: colsums==v, mean rowsums==1/S exactly) ----
__global__ void k_mix(const float* __restrict__ mxa, const float* __restrict__ mxb,
                      const float* __restrict__ mfa, const float* __restrict__ mfb,
                      float* __restrict__ feats) {
    int i = blockIdx.x * 256 + threadIdx.x;
    feats[2 * B_ * CI + i] = LAMF * mxa[i] + ILAMF * mfb[i];
    feats[3 * B_ * CI + i] = LAMF * mxb[i] + ILAMF * mfa[i];
}

__global__ __launch_bounds__(128) void k_metric(const float* __restrict__ feats,
                                                const float* __restrict__ PnT,
                                                const float* __restrict__ pn2,
                                                const int* __restrict__ la,
                                                const int* __restrict__ lb,
                                                float* __restrict__ mo) {
    __shared__ float lds2[2];
    __shared__ float xs[128];
    int blk = blockIdx.x;
    int t = threadIdx.x;
    float xv = feats[(size_t)blk * CI + t];
    float ss = blockSum128(xv * xv, lds2);
    float sc = SCALEF / fmaxf(sqrtf(ss), 1e-12f);
    float xn = xv * sc;
    xs[t] = xn;
    float xn2 = blockSum128(xn * xn, lds2);
    bool active = (t < NB);
    float Dk = 1e30f;
    if (active) {
        float dot = 0.f;
#pragma unroll 8
        for (int e = 0; e < CI; ++e) dot = fmaf(xs[e], PnT[e * NB + t], dot);
        Dk = xn2 + pn2[t] - 2.f * dot;
    }
    float z = active ? -Dk : -1e30f;
    float m = blockMax128(z, lds2);
    float e = active ? expf(z - m) : 0.f;
    float se = blockSum128(e, lds2);
    float lse = m + logf(se);
    int b = blk & 31;
    if (t == 0) mo[blk * 3 + 0] = lse;
    int A = la[b], Bb = lb[b];
    if (t == A) mo[blk * 3 + 1] = Dk;
    if (t == Bb) mo[blk * 3 + 2] = Dk;
}

__global__ __launch_bounds__(128) void k_final(const float* __restrict__ pr,
                                               const float* __restrict__ mo,
                                               float* __restrict__ out) {
    __shared__ float mla[4], mlb[4];
    int t = threadIdx.x;
    const float* m = mo + t * 3;
    float ula = m[0] + m[1];
    float ulb = m[0] + m[2];
#pragma unroll
    for (int off = 16; off > 0; off >>= 1) {
        ula += __shfl_down(ula, off, 32);
        ulb += __shfl_down(ulb, off, 32);
    }
    if ((t & 31) == 0) { mla[t >> 5] = ula * (1.f / 32.f); mlb[t >> 5] = ulb * (1.f / 32.f); }
    __syncthreads();
    if (t == 0) {
        float lxa = pr[0] * (1.f / 4194304.f);
        float lxb = pr[1] * (1.f / 4194304.f);
        float lca = mla[0];
        float lcb = mlb[1];
        float lcma = LAMF * mla[2] + ILAMF * mlb[2];
        float lcmb = LAMF * mlb[3] + ILAMF * mla[3];
        out[0] = lxa + lxb + lca + lcb + lcma + lcmb;
        out[1] = lxa; out[2] = lxb; out[3] = lca; out[4] = lcb; out[5] = lcma; out[6] = lcmb;
    }
}

extern "C" void kernel_launch(void* const* d_in, const int* in_sizes, int n_in,
                              void* d_out, int out_size, void* d_ws, size_t ws_size,
                              hipStream_t stream) {
    const float* xa = (const float*)d_in[0];
    const float* xb = (const float*)d_in[1];
    const int* la = (const int*)d_in[2];
    const int* lb = (const int*)d_in[3];
    const float* P = (const float*)d_in[4];
    const float* We = (const float*)d_in[5];
    const float* Wf = (const float*)d_in[6];
    const float* Wd = (const float*)d_in[7];

    char* w = (char*)d_ws;
    const size_t XPAD_B = XSZ * 2 * sizeof(u16);     // 18,939,904
    const size_t CPAD_B = CSZ * 2 * sizeof(u16);     // 10,616,832
    const size_t AW_B = (size_t)294912 * 2;
    u16* xpad = (u16*)w;                 w += XPAD_B;
    u16* cpad = (u16*)w;                 w += CPAD_B;
    u16* A1 = (u16*)w;                   w += AW_B;
    u16* A2 = (u16*)w;                   w += AW_B;
    u16* A3 = (u16*)w;                   w += AW_B;
    float* PnT = (float*)w;              w += 12800 * 4;
    float* pn2 = (float*)w;              w += 128 * 4;
    float* feats = (float*)w;            w += 16384 * 4;   // [4][32][128]
    float* meanbuf = (float*)w;          w += 16384 * 4;   // [2 kind][2 ab][32][128]
    float* pr = (float*)w;               w += 16 * 4;
    float* mo = (float*)w;               w += 384 * 4;
    float* out = (float*)d_out;

    hipMemsetAsync(xpad, 0, XPAD_B, stream);
    hipMemsetAsync(cpad, 0, CPAD_B, stream);
    hipMemsetAsync(feats, 0, 2 * B_ * CI * sizeof(float), stream);
    hipMemsetAsync(meanbuf, 0, 16384 * sizeof(float), stream);
    hipMemsetAsync(pr, 0, 2 * sizeof(float), stream);

    k_prep_w<<<1152, 256, 0, stream>>>(We, Wf, Wd, A1, A2, A3);
    k_prox<<<NB, 128, 0, stream>>>(P, PnT, pn2);
    k_xpose<<<dim3(32, 16, 2), 256, 0, stream>>>(xa, xb, xpad, meanbuf);
    k_conv1<<<dim3(8, 32, 2), 256, 0, stream>>>(xpad, A1, cpad);
    k_cde<<<dim3(4, 32, 4), 256, 0, stream>>>(cpad, A2, A3, xpad, feats, pr);
    k_mix<<<16, 256, 0, stream>>>(meanbuf, meanbuf + 4096, meanbuf + 8192, meanbuf + 12288, feats);
    k_metric<<<128, 128, 0, stream>>>(feats, PnT, pn2, la, lb, mo);
    k_final<<<1, 128, 0, stream>>>(pr, mo, out);
}